// Round 9
// baseline (445.071 us; speedup 1.0000x reference)
//
#include <hip/hip_runtime.h>
#include <math.h>

#define NN 50000
#define EE 640000
#define IND 23
#define HID 128
#define MIDD 64
#define NCLS 12
#define NB 49          // ceil(NN / 1024) scan chunks
#define QS 32766.0f
#define INVQS (1.0f / 32766.0f)

typedef short short8v __attribute__((ext_vector_type(8)));

// ---- graph build ----------------------------------------------------------

__global__ void k_count(const int* __restrict__ dst, int* __restrict__ cnt, int e) {
    int i = blockIdx.x * blockDim.x + threadIdx.x;
    if (i < e) atomicAdd(&cnt[dst[i]], 1);
}

__global__ __launch_bounds__(256) void k_scan_local(const int* __restrict__ cnt,
                                                    int* __restrict__ row_ptr,
                                                    float* __restrict__ dinv,
                                                    int* __restrict__ sums) {
    __shared__ int wtot[4];
    const int tid = threadIdx.x;
    const int wid = tid >> 6, lane = tid & 63;
    const int base = blockIdx.x * 1024 + tid * 4;
    int v[4];
#pragma unroll
    for (int t = 0; t < 4; ++t) {
        int i = base + t;
        v[t] = (i < NN) ? cnt[i] : 0;
        if (i < NN) dinv[i] = rsqrtf((float)v[t] + 1.0f);  // +1 self loop
    }
    int slocal = v[0] + v[1] + v[2] + v[3];
    int val = slocal;
#pragma unroll
    for (int off = 1; off < 64; off <<= 1) {
        int t = __shfl_up(val, off, 64);
        if (lane >= off) val += t;
    }
    if (lane == 63) wtot[wid] = val;
    __syncthreads();
    int woff = 0;
#pragma unroll
    for (int w = 0; w < 4; ++w) woff += (w < wid) ? wtot[w] : 0;
    int run = woff + val - slocal;
#pragma unroll
    for (int t = 0; t < 4; ++t) {
        int i = base + t;
        if (i < NN) row_ptr[i] = run;
        run += v[t];
    }
    if (tid == 255) sums[blockIdx.x] = woff + val;
}

__global__ void k_scan_sums(const int* __restrict__ sums, int* __restrict__ offs,
                            int* __restrict__ row_ptr) {
    const int lane = threadIdx.x;
    int v = (lane < NB) ? sums[lane] : 0;
    int val = v;
#pragma unroll
    for (int off = 1; off < 64; off <<= 1) {
        int t = __shfl_up(val, off, 64);
        if (lane >= off) val += t;
    }
    if (lane < NB) offs[lane] = val - v;
    if (lane == NB - 1) row_ptr[NN] = val;
}

__global__ __launch_bounds__(256) void k_scan_apply(int* __restrict__ row_ptr,
                                                    const int* __restrict__ offs,
                                                    int* __restrict__ cursor) {
    const int base = blockIdx.x * 1024 + threadIdx.x * 4;
    const int o = offs[blockIdx.x];
#pragma unroll
    for (int t = 0; t < 4; ++t) {
        int i = base + t;
        if (i < NN) {
            int rp = row_ptr[i] + o;
            row_ptr[i] = rp;
            cursor[i] = rp;
        }
    }
}

__global__ void k_fill(const int* __restrict__ src, const int* __restrict__ dst,
                       int* __restrict__ cursor, int* __restrict__ e_src, int e) {
    int i = blockIdx.x * blockDim.x + threadIdx.x;
    if (i < e) {
        int d = dst[i];
        int pos = atomicAdd(&cursor[d], 1);
        e_src[pos] = src[i];
    }
}

// pad x rows 23 -> 32 floats, pre-scaled by dinv[node] (rank-1 norm fold)
__global__ __launch_bounds__(256) void k_pad(const float* __restrict__ x,
                                             const float* __restrict__ dinv,
                                             float* __restrict__ xp) {
    int i = blockIdx.x * 256 + threadIdx.x;   // over NN*32
    int node = i >> 5, f = i & 31;
    xp[i] = (f < IND) ? x[node * IND + f] * dinv[node] : 0.f;
}

// ---- layer 1 fused: q1 = quant( tanh( (A @ x) @ W1 + b1 ) ) ---------------
// wave per node; 8 edges in flight. Remainder shfl runs wave-uniform
// (ds_bpermute from an EXEC-masked source lane is undefined — round-6/7 bug).
__global__ __launch_bounds__(256) void k_l1(const float* __restrict__ xp,
                                            const float* __restrict__ W1,
                                            const float* __restrict__ b1,
                                            const int* __restrict__ row_ptr,
                                            const int* __restrict__ e_src,
                                            const float* __restrict__ dinv,
                                            short* __restrict__ outq) {
    const int tid = threadIdx.x;
    const int i = blockIdx.x * 4 + (tid >> 6);
    const int lane = tid & 63;
    const int slot = lane >> 3;     // 8 edge slots
    const int f = lane & 7;         // float4 index within 32-float row
    const float4* xp4 = (const float4*)xp;
    const int beg = row_ptr[i];
    const int deg = row_ptr[i + 1] - beg;
    float4 acc = make_float4(0.f, 0.f, 0.f, 0.f);
    for (int base = 0; base < deg; base += 64) {
        const int cnt = min(64, deg - base);
        int s_l = 0;
        if (lane < cnt) s_l = e_src[beg + base + lane];
        int e = 0;
        for (; e + 8 <= cnt; e += 8) {
            int s = __shfl(s_l, e + slot, 64);
            float4 v = xp4[s * 8 + f];
            acc.x += v.x; acc.y += v.y; acc.z += v.z; acc.w += v.w;
        }
        if (e < cnt) {                          // wave-uniform shfl
            int s = __shfl(s_l, e + slot, 64);
            if (e + slot < cnt) {
                float4 v = xp4[s * 8 + f];
                acc.x += v.x; acc.y += v.y; acc.z += v.z; acc.w += v.w;
            }
        }
    }
#pragma unroll
    for (int off = 32; off >= 8; off >>= 1) {
        acc.x += __shfl_down(acc.x, off, 64);
        acc.y += __shfl_down(acc.y, off, 64);
        acc.z += __shfl_down(acc.z, off, 64);
        acc.w += __shfl_down(acc.w, off, 64);
    }
    const float di = dinv[i];
    if (lane < 8) {
        float4 v = xp4[i * 8 + lane];   // self row (pre-folded)
        acc.x = (acc.x + v.x) * di; acc.y = (acc.y + v.y) * di;
        acc.z = (acc.z + v.z) * di; acc.w = (acc.w + v.w) * di;
    }
    float a0 = b1[lane], a1 = b1[lane + 64];
#pragma unroll
    for (int k = 0; k < IND; ++k) {
        float comp = ((k & 3) == 0) ? acc.x : ((k & 3) == 1) ? acc.y
                   : ((k & 3) == 2) ? acc.z : acc.w;
        float xk = __shfl(comp, k >> 2, 64);
        a0 += xk * W1[k * HID + lane];
        a1 += xk * W1[k * HID + lane + 64];
    }
    outq[i * HID + lane]      = (short)__float2int_rn(tanhf(a0) * QS);
    outq[i * HID + lane + 64] = (short)__float2int_rn(tanhf(a1) * QS);
}

// ---- fused GCN layer: agg(int16) -> LDS -> GEMM(+tanh) --------------------
// block = 64 nodes, 4 waves. Phase 1: each wave aggregates 16 nodes (full-wave
// gather: 4 edge slots x 16 short8 lanes) into LDS Hs (fp32, stride 132).
// Phase 2: tiled GEMM from LDS + tanh. LAST=false: quantize -> qout.
// LAST=true: tanh back to Hs, then fused head 128->64->12 -> outp.
template <bool LAST>
__global__ __launch_bounds__(256) void k_layer(const short* __restrict__ qin,
                                               const float* __restrict__ W,
                                               const float* __restrict__ bias,
                                               const int* __restrict__ row_ptr,
                                               const int* __restrict__ e_src,
                                               const float* __restrict__ dinv,
                                               short* __restrict__ qout,
                                               const float* __restrict__ Wc1,
                                               const float* __restrict__ bc1,
                                               const float* __restrict__ Wc2,
                                               const float* __restrict__ bc2,
                                               float* __restrict__ outp) {
    __shared__ float Hs[64 * 132];   // agg rows fp32 (padded stride)
    __shared__ float Ws[4160];       // W chunk (32x128) / reused as ms (64x65)
    const int tid = threadIdx.x;
    const int b0 = blockIdx.x * 64;
    const int wv = tid >> 6;        // wave 0..3
    const int lane = tid & 63;
    const int slot = lane >> 4;     // 4 edge slots
    const int f = lane & 15;        // short8 index within 128-short row
    const short8v* h8 = (const short8v*)qin;

    // ---- phase 1: aggregate 16 nodes per wave into Hs ----
    for (int t = 0; t < 16; ++t) {
        const int row = wv * 16 + t;
        const int i = b0 + row;
        if (i < NN) {
            const int beg = row_ptr[i];
            const int deg = row_ptr[i + 1] - beg;
            float facc[8];
#pragma unroll
            for (int c = 0; c < 8; ++c) facc[c] = 0.f;
            for (int base = 0; base < deg; base += 64) {
                const int cnt = min(64, deg - base);
                int s_l = 0; float n_l = 0.f;
                if (lane < cnt) {
                    s_l = e_src[beg + base + lane];
                    n_l = dinv[s_l];
                }
                int e = 0;
#pragma unroll 2
                for (; e + 4 <= cnt; e += 4) {
                    int s = __shfl(s_l, e + slot, 64);
                    float nr = __shfl(n_l, e + slot, 64);
                    short8v v = h8[s * 16 + f];
#pragma unroll
                    for (int c = 0; c < 8; ++c) facc[c] += (float)v[c] * nr;
                }
                if (e < cnt) {                  // wave-uniform shfl
                    int s = __shfl(s_l, e + slot, 64);
                    float nr = __shfl(n_l, e + slot, 64);
                    if (e + slot < cnt) {
                        short8v v = h8[s * 16 + f];
#pragma unroll
                        for (int c = 0; c < 8; ++c) facc[c] += (float)v[c] * nr;
                    }
                }
            }
#pragma unroll
            for (int off = 32; off >= 16; off >>= 1)
#pragma unroll
                for (int c = 0; c < 8; ++c) facc[c] += __shfl_down(facc[c], off, 64);
            if (lane < 16) {
                const float di = dinv[i];
                const float sc = di * INVQS;
                short8v v = h8[i * 16 + lane];  // self row
                float* dstp = &Hs[row * 132 + lane * 8];
                float4 o0, o1;
                o0.x = (facc[0] + di * (float)v[0]) * sc;
                o0.y = (facc[1] + di * (float)v[1]) * sc;
                o0.z = (facc[2] + di * (float)v[2]) * sc;
                o0.w = (facc[3] + di * (float)v[3]) * sc;
                o1.x = (facc[4] + di * (float)v[4]) * sc;
                o1.y = (facc[5] + di * (float)v[5]) * sc;
                o1.z = (facc[6] + di * (float)v[6]) * sc;
                o1.w = (facc[7] + di * (float)v[7]) * sc;
                *(float4*)dstp = o0;
                *(float4*)(dstp + 4) = o1;
            }
        } else if (lane < 16) {
            float* dstp = &Hs[row * 132 + lane * 8];
            *(float4*)dstp = make_float4(0.f, 0.f, 0.f, 0.f);
            *(float4*)(dstp + 4) = make_float4(0.f, 0.f, 0.f, 0.f);
        }
    }
    __syncthreads();

    // ---- phase 2: GEMM from LDS ----
    const int ng = tid >> 4;        // node group 0..15 (4 rows)
    const int cg = tid & 15;        // col group 0..15 (8 cols)
    const float4* W4 = (const float4*)W;
    float acc[4][8];
#pragma unroll
    for (int m = 0; m < 4; ++m)
#pragma unroll
        for (int c = 0; c < 8; ++c) acc[m][c] = 0.f;

    for (int ks = 0; ks < HID; ks += 32) {
#pragma unroll
        for (int t = 0; t < 4; ++t) {
            int id = t * 256 + tid;
            int row = id >> 5;
            int c4 = id & 31;
            *(float4*)&Ws[row * 128 + c4 * 4] = W4[(ks + row) * 32 + c4];
        }
        __syncthreads();
#pragma unroll 8
        for (int kk = 0; kk < 32; ++kk) {
            float4 w0 = *(float4*)&Ws[kk * 128 + cg * 8];
            float4 w1 = *(float4*)&Ws[kk * 128 + cg * 8 + 4];
#pragma unroll
            for (int m = 0; m < 4; ++m) {
                float hv = Hs[(ng * 4 + m) * 132 + ks + kk];
                acc[m][0] += hv * w0.x; acc[m][1] += hv * w0.y;
                acc[m][2] += hv * w0.z; acc[m][3] += hv * w0.w;
                acc[m][4] += hv * w1.x; acc[m][5] += hv * w1.y;
                acc[m][6] += hv * w1.z; acc[m][7] += hv * w1.w;
            }
        }
        __syncthreads();
    }
    const float4* b4 = (const float4*)bias;
    float4 bb0 = b4[cg * 2], bb1 = b4[cg * 2 + 1];
#pragma unroll
    for (int m = 0; m < 4; ++m) {
        int row = ng * 4 + m;
        int node = b0 + row;
        float t0 = tanhf(acc[m][0] + bb0.x);
        float t1 = tanhf(acc[m][1] + bb0.y);
        float t2 = tanhf(acc[m][2] + bb0.z);
        float t3 = tanhf(acc[m][3] + bb0.w);
        float t4 = tanhf(acc[m][4] + bb1.x);
        float t5 = tanhf(acc[m][5] + bb1.y);
        float t6 = tanhf(acc[m][6] + bb1.z);
        float t7 = tanhf(acc[m][7] + bb1.w);
        if (!LAST) {
            if (node < NN) {
                short8v qv;
                qv[0] = (short)__float2int_rn(t0 * QS);
                qv[1] = (short)__float2int_rn(t1 * QS);
                qv[2] = (short)__float2int_rn(t2 * QS);
                qv[3] = (short)__float2int_rn(t3 * QS);
                qv[4] = (short)__float2int_rn(t4 * QS);
                qv[5] = (short)__float2int_rn(t5 * QS);
                qv[6] = (short)__float2int_rn(t6 * QS);
                qv[7] = (short)__float2int_rn(t7 * QS);
                ((short8v*)qout)[node * 16 + cg] = qv;
            }
        } else {
            float* dstp = &Hs[row * 132 + cg * 8];   // safe: all reads done (sync above)
            *(float4*)dstp = make_float4(t0, t1, t2, t3);
            *(float4*)(dstp + 4) = make_float4(t4, t5, t6, t7);
        }
    }

    if (LAST) {
        __syncthreads();
        // ---- head phase A: ms = h3 @ Wc1 + bc1  (ms reuses Ws, stride 65) ----
        const int c = tid & 63;
        const int q4 = tid >> 6;
        float a2[16];
#pragma unroll
        for (int t = 0; t < 16; ++t) a2[t] = 0.f;
        for (int k = 0; k < HID; ++k) {
            float w = Wc1[k * MIDD + c];
#pragma unroll
            for (int t = 0; t < 16; ++t) a2[t] += Hs[(q4 * 16 + t) * 132 + k] * w;
        }
        float bb = bc1[c];
#pragma unroll
        for (int t = 0; t < 16; ++t) Ws[(q4 * 16 + t) * 65 + c] = a2[t] + bb;
        __syncthreads();
        // ---- head phase B: out = ms @ Wc2 + bc2 ----
#pragma unroll
        for (int t = 0; t < 3; ++t) {
            int idx = tid + 256 * t;           // < 768 = 64*12
            int m = idx / NCLS;
            int cls = idx - m * NCLS;
            int node = b0 + m;
            if (node < NN) {
                float o = bc2[cls];
#pragma unroll 8
                for (int k = 0; k < MIDD; ++k) o += Ws[m * 65 + k] * Wc2[k * NCLS + cls];
                outp[node * NCLS + cls] = o;
            }
        }
    }
}

// ---- launch ---------------------------------------------------------------

extern "C" void kernel_launch(void* const* d_in, const int* in_sizes, int n_in,
                              void* d_out, int out_size, void* d_ws, size_t ws_size,
                              hipStream_t stream) {
    const float* x    = (const float*)d_in[0];
    const int*   edge = (const int*)d_in[1];
    const int*   src  = edge;
    const int*   dst  = edge + EE;
    const float* W1  = (const float*)d_in[2];  const float* b1  = (const float*)d_in[3];
    const float* W2  = (const float*)d_in[4];  const float* b2  = (const float*)d_in[5];
    const float* W3  = (const float*)d_in[6];  const float* b3  = (const float*)d_in[7];
    const float* Wc1 = (const float*)d_in[8];  const float* bc1 = (const float*)d_in[9];
    const float* Wc2 = (const float*)d_in[10]; const float* bc2 = (const float*)d_in[11];
    float* outp = (float*)d_out;

    char* p = (char*)d_ws;
    int*   cnt     = (int*)p;   p += 200064;          // NN ints, padded
    int*   row_ptr = (int*)p;   p += 200064;          // NN+1 ints, padded
    float* dinv    = (float*)p; p += 200064;
    int*   sums    = (int*)p;   p += 256;
    int*   offs    = (int*)p;   p += 256;
    int*   e_src   = (int*)p;   p += (size_t)EE * 4;
    float* xp      = (float*)p; p += (size_t)NN * 32 * 4;    // padded pre-folded x
    short* q1      = (short*)p; p += (size_t)NN * HID * 2;   // int16 tanh layer 1
    short* q2      = (short*)p; p += (size_t)NN * HID * 2;   // int16 tanh layer 2

    // graph build
    hipMemsetAsync(cnt, 0, (size_t)NN * 4, stream);
    k_count     <<<(EE + 255) / 256, 256, 0, stream>>>(dst, cnt, EE);
    k_scan_local<<<NB, 256, 0, stream>>>(cnt, row_ptr, dinv, sums);
    k_scan_sums <<<1, 64, 0, stream>>>(sums, offs, row_ptr);
    k_scan_apply<<<NB, 256, 0, stream>>>(row_ptr, offs, cnt);   // cnt becomes cursor
    k_fill      <<<(EE + 255) / 256, 256, 0, stream>>>(src, dst, cnt, e_src, EE);
    k_pad       <<<(NN * 32) / 256, 256, 0, stream>>>(x, dinv, xp);

    // layer 1: q1 = quant(tanh((A@x)@W1 + b1))
    k_l1<<<NN / 4, 256, 0, stream>>>(xp, W1, b1, row_ptr, e_src, dinv, q1);
    // layer 2 fused: agg(q1) -> gemm+tanh -> q2
    k_layer<false><<<(NN + 63) / 64, 256, 0, stream>>>(
        q1, W2, b2, row_ptr, e_src, dinv, q2,
        nullptr, nullptr, nullptr, nullptr, nullptr);
    // layer 3 + head fused: agg(q2) -> gemm+tanh -> 128->64->12 -> out
    k_layer<true><<<(NN + 63) / 64, 256, 0, stream>>>(
        q2, W3, b3, row_ptr, e_src, dinv, nullptr,
        Wc1, bc1, Wc2, bc2, outp);
}

// Round 10
// 386.308 us; speedup vs baseline: 1.1521x; 1.1521x over previous
//
#include <hip/hip_runtime.h>
#include <math.h>

#define NN 50000
#define EE 640000
#define IND 23
#define HID 128
#define MIDD 64
#define NCLS 12
#define NB 49          // ceil(NN / 1024) scan chunks
#define QS 32766.0f
#define INVQS (1.0f / 32766.0f)

typedef short short8v __attribute__((ext_vector_type(8)));

// ---- graph build ----------------------------------------------------------

__global__ void k_count(const int* __restrict__ dst, int* __restrict__ cnt, int e) {
    int i = blockIdx.x * blockDim.x + threadIdx.x;
    if (i < e) atomicAdd(&cnt[dst[i]], 1);
}

__global__ __launch_bounds__(256) void k_scan_local(const int* __restrict__ cnt,
                                                    int* __restrict__ row_ptr,
                                                    float* __restrict__ dinv,
                                                    int* __restrict__ sums) {
    __shared__ int wtot[4];
    const int tid = threadIdx.x;
    const int wid = tid >> 6, lane = tid & 63;
    const int base = blockIdx.x * 1024 + tid * 4;
    int v[4];
#pragma unroll
    for (int t = 0; t < 4; ++t) {
        int i = base + t;
        v[t] = (i < NN) ? cnt[i] : 0;
        if (i < NN) dinv[i] = rsqrtf((float)v[t] + 1.0f);  // +1 self loop
    }
    int slocal = v[0] + v[1] + v[2] + v[3];
    int val = slocal;
#pragma unroll
    for (int off = 1; off < 64; off <<= 1) {
        int t = __shfl_up(val, off, 64);
        if (lane >= off) val += t;
    }
    if (lane == 63) wtot[wid] = val;
    __syncthreads();
    int woff = 0;
#pragma unroll
    for (int w = 0; w < 4; ++w) woff += (w < wid) ? wtot[w] : 0;
    int run = woff + val - slocal;
#pragma unroll
    for (int t = 0; t < 4; ++t) {
        int i = base + t;
        if (i < NN) row_ptr[i] = run;
        run += v[t];
    }
    if (tid == 255) sums[blockIdx.x] = woff + val;
}

__global__ void k_scan_sums(const int* __restrict__ sums, int* __restrict__ offs,
                            int* __restrict__ row_ptr) {
    const int lane = threadIdx.x;
    int v = (lane < NB) ? sums[lane] : 0;
    int val = v;
#pragma unroll
    for (int off = 1; off < 64; off <<= 1) {
        int t = __shfl_up(val, off, 64);
        if (lane >= off) val += t;
    }
    if (lane < NB) offs[lane] = val - v;
    if (lane == NB - 1) row_ptr[NN] = val;
}

// stage 3: add chunk offsets to row_ptr; init fill cursor; ALSO pad x rows
// 23 -> 32 floats pre-scaled by dinv (independent work, merged to save a launch)
__global__ __launch_bounds__(256) void k_scan_apply(int* __restrict__ row_ptr,
                                                    const int* __restrict__ offs,
                                                    int* __restrict__ cursor,
                                                    const float* __restrict__ x,
                                                    const float* __restrict__ dinv,
                                                    float* __restrict__ xp) {
    const int tid = threadIdx.x;
    const int base = blockIdx.x * 1024 + tid * 4;
    const int o = offs[blockIdx.x];
#pragma unroll
    for (int t = 0; t < 4; ++t) {
        int i = base + t;
        if (i < NN) {
            int rp = row_ptr[i] + o;
            row_ptr[i] = rp;
            cursor[i] = rp;
        }
    }
    // pad/fold x for this block's 1024 nodes: 32768 elems, 128 per thread
    const int xbase = blockIdx.x * 32768;
    for (int t = 0; t < 128; ++t) {
        int idx = xbase + t * 256 + tid;
        if (idx < NN * 32) {
            int node = idx >> 5, f = idx & 31;
            xp[idx] = (f < IND) ? x[node * IND + f] * dinv[node] : 0.f;
        }
    }
}

__global__ void k_fill(const int* __restrict__ src, const int* __restrict__ dst,
                       int* __restrict__ cursor, int* __restrict__ e_src, int e) {
    int i = blockIdx.x * blockDim.x + threadIdx.x;
    if (i < e) {
        int d = dst[i];
        int pos = atomicAdd(&cursor[d], 1);
        e_src[pos] = src[i];
    }
}

// ---- layer 1 fused: q1 = quant( tanh( (A @ x) @ W1 + b1 ) ) ---------------
// wave per node; 8 edges in flight. Remainder shfl runs wave-uniform
// (ds_bpermute from an EXEC-masked source lane is undefined — round-6/7 bug).
__global__ __launch_bounds__(256) void k_l1(const float* __restrict__ xp,
                                            const float* __restrict__ W1,
                                            const float* __restrict__ b1,
                                            const int* __restrict__ row_ptr,
                                            const int* __restrict__ e_src,
                                            const float* __restrict__ dinv,
                                            short* __restrict__ outq) {
    const int tid = threadIdx.x;
    const int i = blockIdx.x * 4 + (tid >> 6);
    const int lane = tid & 63;
    const int slot = lane >> 3;     // 8 edge slots
    const int f = lane & 7;         // float4 index within 32-float row
    const float4* xp4 = (const float4*)xp;
    const int beg = row_ptr[i];
    const int deg = row_ptr[i + 1] - beg;
    float4 acc = make_float4(0.f, 0.f, 0.f, 0.f);
    for (int base = 0; base < deg; base += 64) {
        const int cnt = min(64, deg - base);
        int s_l = 0;
        if (lane < cnt) s_l = e_src[beg + base + lane];
        int e = 0;
        for (; e + 8 <= cnt; e += 8) {
            int s = __shfl(s_l, e + slot, 64);
            float4 v = xp4[s * 8 + f];
            acc.x += v.x; acc.y += v.y; acc.z += v.z; acc.w += v.w;
        }
        if (e < cnt) {                          // wave-uniform shfl
            int s = __shfl(s_l, e + slot, 64);
            if (e + slot < cnt) {
                float4 v = xp4[s * 8 + f];
                acc.x += v.x; acc.y += v.y; acc.z += v.z; acc.w += v.w;
            }
        }
    }
#pragma unroll
    for (int off = 32; off >= 8; off >>= 1) {
        acc.x += __shfl_down(acc.x, off, 64);
        acc.y += __shfl_down(acc.y, off, 64);
        acc.z += __shfl_down(acc.z, off, 64);
        acc.w += __shfl_down(acc.w, off, 64);
    }
    const float di = dinv[i];
    if (lane < 8) {
        float4 v = xp4[i * 8 + lane];   // self row (pre-folded)
        acc.x = (acc.x + v.x) * di; acc.y = (acc.y + v.y) * di;
        acc.z = (acc.z + v.z) * di; acc.w = (acc.w + v.w) * di;
    }
    float a0 = b1[lane], a1 = b1[lane + 64];
#pragma unroll
    for (int k = 0; k < IND; ++k) {
        float comp = ((k & 3) == 0) ? acc.x : ((k & 3) == 1) ? acc.y
                   : ((k & 3) == 2) ? acc.z : acc.w;
        float xk = __shfl(comp, k >> 2, 64);
        a0 += xk * W1[k * HID + lane];
        a1 += xk * W1[k * HID + lane + 64];
    }
    outq[i * HID + lane]      = (short)__float2int_rn(tanhf(a0) * QS);
    outq[i * HID + lane + 64] = (short)__float2int_rn(tanhf(a1) * QS);
}

// ---- aggregation over int16 tanh rows (lean: 12 VGPR, 0 LDS, 65% occ) -----
// aggf_i = dinv_i * ( sum_s dinv_s*q_s + dinv_i*q_i ) / QS
__global__ __launch_bounds__(256) void k_aggq(const short* __restrict__ hq,
                                              const int* __restrict__ row_ptr,
                                              const int* __restrict__ e_src,
                                              const float* __restrict__ dinv,
                                              float* __restrict__ aggf) {
    const int tid = threadIdx.x;
    const int i = blockIdx.x * 4 + (tid >> 6);
    const int lane = tid & 63;
    const int slot = lane >> 4;     // 4 edge slots
    const int f = lane & 15;        // short8 index within 128-short row
    const short8v* h8 = (const short8v*)hq;
    const int beg = row_ptr[i];
    const int deg = row_ptr[i + 1] - beg;
    float facc[8];
#pragma unroll
    for (int t = 0; t < 8; ++t) facc[t] = 0.f;
    for (int base = 0; base < deg; base += 64) {
        const int cnt = min(64, deg - base);
        int s_l = 0; float n_l = 0.f;
        if (lane < cnt) {
            s_l = e_src[beg + base + lane];
            n_l = dinv[s_l];
        }
        int e = 0;
#pragma unroll 2
        for (; e + 4 <= cnt; e += 4) {
            int s = __shfl(s_l, e + slot, 64);
            float nr = __shfl(n_l, e + slot, 64);
            short8v v = h8[s * 16 + f];
#pragma unroll
            for (int t = 0; t < 8; ++t) facc[t] += (float)v[t] * nr;
        }
        if (e < cnt) {                          // wave-uniform shfl
            int s = __shfl(s_l, e + slot, 64);
            float nr = __shfl(n_l, e + slot, 64);
            if (e + slot < cnt) {
                short8v v = h8[s * 16 + f];
#pragma unroll
                for (int t = 0; t < 8; ++t) facc[t] += (float)v[t] * nr;
            }
        }
    }
#pragma unroll
    for (int off = 32; off >= 16; off >>= 1)
#pragma unroll
        for (int t = 0; t < 8; ++t) facc[t] += __shfl_down(facc[t], off, 64);
    if (lane < 16) {
        const float di = dinv[i];
        const float sc = di * INVQS;
        short8v v = h8[i * 16 + lane];          // self row
        float4 o0, o1;
        o0.x = (facc[0] + di * (float)v[0]) * sc;
        o0.y = (facc[1] + di * (float)v[1]) * sc;
        o0.z = (facc[2] + di * (float)v[2]) * sc;
        o0.w = (facc[3] + di * (float)v[3]) * sc;
        o1.x = (facc[4] + di * (float)v[4]) * sc;
        o1.y = (facc[5] + di * (float)v[5]) * sc;
        o1.z = (facc[6] + di * (float)v[6]) * sc;
        o1.w = (facc[7] + di * (float)v[7]) * sc;
        ((float4*)aggf)[i * 32 + lane * 2]     = o0;
        ((float4*)aggf)[i * 32 + lane * 2 + 1] = o1;
    }
}

// ---- tiled 128x128 GEMM + tanh; LAST=false -> int16 quantize to qout;
// LAST=true -> tanh kept in LDS, fused head 128->64->12 -> outp. ------------
// LDS union: K-loop uses Hs[64*36]+Ws[32*128] (25.6KB). LAST head reuses the
// whole buffer as h3[64*132] + ms[64*65] (50.4KB, one dispatch only).
template <bool LAST>
__global__ __launch_bounds__(256) void k_gemmT(const float* __restrict__ hin,
                                               const float* __restrict__ W,
                                               const float* __restrict__ bias,
                                               short* __restrict__ qout,
                                               const float* __restrict__ Wc1,
                                               const float* __restrict__ bc1,
                                               const float* __restrict__ Wc2,
                                               const float* __restrict__ bc2,
                                               float* __restrict__ outp) {
    __shared__ float smem[LAST ? (64 * 132 + 64 * 65) : (64 * 36 + 32 * 128)];
    float* Hs = smem;                 // 64 x 36 (K-loop staging)
    float* Ws = smem + 64 * 36;       // 32 x 128
    const int tid = threadIdx.x;
    const int b0 = blockIdx.x * 64;
    const int ng = tid >> 4;
    const int cg = tid & 15;
    const float4* hin4 = (const float4*)hin;
    const float4* W4 = (const float4*)W;

    float acc[4][8];
#pragma unroll
    for (int m = 0; m < 4; ++m)
#pragma unroll
        for (int c = 0; c < 8; ++c) acc[m][c] = 0.f;

    for (int ks = 0; ks < HID; ks += 32) {
#pragma unroll
        for (int t = 0; t < 2; ++t) {
            int id = t * 256 + tid;
            int row = id >> 3;
            int k4 = id & 7;
            int node = b0 + row;
            float4 v = make_float4(0.f, 0.f, 0.f, 0.f);
            if (node < NN) v = hin4[node * 32 + (ks >> 2) + k4];
            *(float4*)&Hs[row * 36 + k4 * 4] = v;
        }
#pragma unroll
        for (int t = 0; t < 4; ++t) {
            int id = t * 256 + tid;
            int row = id >> 5;
            int c4 = id & 31;
            *(float4*)&Ws[row * 128 + c4 * 4] = W4[(ks + row) * 32 + c4];
        }
        __syncthreads();
#pragma unroll 8
        for (int kk = 0; kk < 32; ++kk) {
            float4 w0 = *(float4*)&Ws[kk * 128 + cg * 8];
            float4 w1 = *(float4*)&Ws[kk * 128 + cg * 8 + 4];
#pragma unroll
            for (int m = 0; m < 4; ++m) {
                float hv = Hs[(ng * 4 + m) * 36 + kk];
                acc[m][0] += hv * w0.x; acc[m][1] += hv * w0.y;
                acc[m][2] += hv * w0.z; acc[m][3] += hv * w0.w;
                acc[m][4] += hv * w1.x; acc[m][5] += hv * w1.y;
                acc[m][6] += hv * w1.z; acc[m][7] += hv * w1.w;
            }
        }
        __syncthreads();
    }
    const float4* b4 = (const float4*)bias;
    float4 bb0 = b4[cg * 2], bb1 = b4[cg * 2 + 1];
    float* h3 = smem;                 // LAST head: 64 x 132 (overlaps Hs/Ws)
    float* ms = smem + 64 * 132;      // 64 x 65
#pragma unroll
    for (int m = 0; m < 4; ++m) {
        int row = ng * 4 + m;
        int node = b0 + row;
        float t0 = tanhf(acc[m][0] + bb0.x);
        float t1 = tanhf(acc[m][1] + bb0.y);
        float t2 = tanhf(acc[m][2] + bb0.z);
        float t3 = tanhf(acc[m][3] + bb0.w);
        float t4 = tanhf(acc[m][4] + bb1.x);
        float t5 = tanhf(acc[m][5] + bb1.y);
        float t6 = tanhf(acc[m][6] + bb1.z);
        float t7 = tanhf(acc[m][7] + bb1.w);
        if (!LAST) {
            if (node < NN) {
                short8v qv;
                qv[0] = (short)__float2int_rn(t0 * QS);
                qv[1] = (short)__float2int_rn(t1 * QS);
                qv[2] = (short)__float2int_rn(t2 * QS);
                qv[3] = (short)__float2int_rn(t3 * QS);
                qv[4] = (short)__float2int_rn(t4 * QS);
                qv[5] = (short)__float2int_rn(t5 * QS);
                qv[6] = (short)__float2int_rn(t6 * QS);
                qv[7] = (short)__float2int_rn(t7 * QS);
                ((short8v*)qout)[node * 16 + cg] = qv;
            }
        } else {
            // write AFTER the K-loop's trailing __syncthreads: all Hs/Ws reads done
            float* dstp = &h3[row * 132 + cg * 8];
            *(float4*)dstp = make_float4(t0, t1, t2, t3);
            *(float4*)(dstp + 4) = make_float4(t4, t5, t6, t7);
        }
    }

    if (LAST) {
        __syncthreads();
        // head phase A: ms = h3 @ Wc1 + bc1. One wave per 16-row group;
        // all 64 lanes of a wave read the same h3 address (broadcast, free).
        const int c = tid & 63;
        const int q4 = tid >> 6;
        float a2[16];
#pragma unroll
        for (int t = 0; t < 16; ++t) a2[t] = 0.f;
        for (int k = 0; k < HID; ++k) {
            float w = Wc1[k * MIDD + c];
#pragma unroll
            for (int t = 0; t < 16; ++t) a2[t] += h3[(q4 * 16 + t) * 132 + k] * w;
        }
        float bb = bc1[c];
#pragma unroll
        for (int t = 0; t < 16; ++t) ms[(q4 * 16 + t) * 65 + c] = a2[t] + bb;
        __syncthreads();
        // head phase B: out = ms @ Wc2 + bc2  (768 outputs, 3 per thread)
#pragma unroll
        for (int t = 0; t < 3; ++t) {
            int idx = tid + 256 * t;
            int m = idx / NCLS;
            int cls = idx - m * NCLS;
            int node = b0 + m;
            if (node < NN) {
                float o = bc2[cls];
#pragma unroll 8
                for (int k = 0; k < MIDD; ++k) o += ms[m * 65 + k] * Wc2[k * NCLS + cls];
                outp[node * NCLS + cls] = o;
            }
        }
    }
}

// ---- launch ---------------------------------------------------------------

extern "C" void kernel_launch(void* const* d_in, const int* in_sizes, int n_in,
                              void* d_out, int out_size, void* d_ws, size_t ws_size,
                              hipStream_t stream) {
    const float* x    = (const float*)d_in[0];
    const int*   edge = (const int*)d_in[1];
    const int*   src  = edge;
    const int*   dst  = edge + EE;
    const float* W1  = (const float*)d_in[2];  const float* b1  = (const float*)d_in[3];
    const float* W2  = (const float*)d_in[4];  const float* b2  = (const float*)d_in[5];
    const float* W3  = (const float*)d_in[6];  const float* b3  = (const float*)d_in[7];
    const float* Wc1 = (const float*)d_in[8];  const float* bc1 = (const float*)d_in[9];
    const float* Wc2 = (const float*)d_in[10]; const float* bc2 = (const float*)d_in[11];
    float* outp = (float*)d_out;

    char* p = (char*)d_ws;
    int*   cnt     = (int*)p;   p += 200064;          // NN ints, padded
    int*   row_ptr = (int*)p;   p += 200064;          // NN+1 ints, padded
    float* dinv    = (float*)p; p += 200064;
    int*   sums    = (int*)p;   p += 256;
    int*   offs    = (int*)p;   p += 256;
    int*   e_src   = (int*)p;   p += (size_t)EE * 4;
    float* xp      = (float*)p; p += (size_t)NN * 32 * 4;    // padded pre-folded x
    short* q1      = (short*)p; p += (size_t)NN * HID * 2;   // int16 tanh layer 1
    short* q2      = (short*)p; p += (size_t)NN * HID * 2;   // int16 tanh layer 2
    float* aggf    = (float*)p; p += (size_t)NN * HID * 4;   // fp32 agg buffer

    // graph build (+x pad folded into scan_apply)
    hipMemsetAsync(cnt, 0, (size_t)NN * 4, stream);
    k_count     <<<(EE + 255) / 256, 256, 0, stream>>>(dst, cnt, EE);
    k_scan_local<<<NB, 256, 0, stream>>>(cnt, row_ptr, dinv, sums);
    k_scan_sums <<<1, 64, 0, stream>>>(sums, offs, row_ptr);
    k_scan_apply<<<NB, 256, 0, stream>>>(row_ptr, offs, cnt, x, dinv, xp);
    k_fill      <<<(EE + 255) / 256, 256, 0, stream>>>(src, dst, cnt, e_src, EE);

    // layer 1: q1 = quant(tanh((A@x)@W1 + b1))
    k_l1<<<NN / 4, 256, 0, stream>>>(xp, W1, b1, row_ptr, e_src, dinv, q1);
    // layer 2: agg(q1) -> gemm+tanh -> q2
    k_aggq        <<<NN / 4, 256, 0, stream>>>(q1, row_ptr, e_src, dinv, aggf);
    k_gemmT<false><<<(NN + 63) / 64, 256, 0, stream>>>(aggf, W2, b2, q2,
                                                       nullptr, nullptr, nullptr, nullptr, nullptr);
    // layer 3 + head: agg(q2) -> gemm+tanh -> 128->64->12 -> out
    k_aggq        <<<NN / 4, 256, 0, stream>>>(q2, row_ptr, e_src, dinv, aggf);
    k_gemmT<true> <<<(NN + 63) / 64, 256, 0, stream>>>(aggf, W3, b3, nullptr,
                                                       Wc1, bc1, Wc2, bc2, outp);
}

// Round 11
// 371.288 us; speedup vs baseline: 1.1987x; 1.0405x over previous
//
#include <hip/hip_runtime.h>
#include <math.h>

#define NN 50000
#define EE 640000
#define IND 23
#define HID 128
#define MIDD 64
#define NCLS 12
#define NB 49          // ceil(NN / 1024) scan chunks
#define QS 32766.0f
#define INVQS (1.0f / 32766.0f)

typedef short short8v __attribute__((ext_vector_type(8)));

// ---- graph build ----------------------------------------------------------

__global__ void k_count(const int* __restrict__ dst, int* __restrict__ cnt, int e) {
    int i = blockIdx.x * blockDim.x + threadIdx.x;
    if (i < e) atomicAdd(&cnt[dst[i]], 1);
}

__global__ __launch_bounds__(256) void k_scan_local(const int* __restrict__ cnt,
                                                    int* __restrict__ row_ptr,
                                                    float* __restrict__ dinv,
                                                    int* __restrict__ sums) {
    __shared__ int wtot[4];
    const int tid = threadIdx.x;
    const int wid = tid >> 6, lane = tid & 63;
    const int base = blockIdx.x * 1024 + tid * 4;
    int v[4];
#pragma unroll
    for (int t = 0; t < 4; ++t) {
        int i = base + t;
        v[t] = (i < NN) ? cnt[i] : 0;
        if (i < NN) dinv[i] = rsqrtf((float)v[t] + 1.0f);  // +1 self loop
    }
    int slocal = v[0] + v[1] + v[2] + v[3];
    int val = slocal;
#pragma unroll
    for (int off = 1; off < 64; off <<= 1) {
        int t = __shfl_up(val, off, 64);
        if (lane >= off) val += t;
    }
    if (lane == 63) wtot[wid] = val;
    __syncthreads();
    int woff = 0;
#pragma unroll
    for (int w = 0; w < 4; ++w) woff += (w < wid) ? wtot[w] : 0;
    int run = woff + val - slocal;
#pragma unroll
    for (int t = 0; t < 4; ++t) {
        int i = base + t;
        if (i < NN) row_ptr[i] = run;
        run += v[t];
    }
    if (tid == 255) sums[blockIdx.x] = woff + val;
}

__global__ void k_scan_sums(const int* __restrict__ sums, int* __restrict__ offs,
                            int* __restrict__ row_ptr) {
    const int lane = threadIdx.x;
    int v = (lane < NB) ? sums[lane] : 0;
    int val = v;
#pragma unroll
    for (int off = 1; off < 64; off <<= 1) {
        int t = __shfl_up(val, off, 64);
        if (lane >= off) val += t;
    }
    if (lane < NB) offs[lane] = val - v;
    if (lane == NB - 1) row_ptr[NN] = val;
}

// stage 3: add chunk offsets to row_ptr; init fill cursor; ALSO pad/fold x
// rows 23 -> 32 floats pre-scaled by dinv (independent work, saves a launch)
__global__ __launch_bounds__(256) void k_scan_apply(int* __restrict__ row_ptr,
                                                    const int* __restrict__ offs,
                                                    int* __restrict__ cursor,
                                                    const float* __restrict__ x,
                                                    const float* __restrict__ dinv,
                                                    float* __restrict__ xp) {
    const int tid = threadIdx.x;
    const int base = blockIdx.x * 1024 + tid * 4;
    const int o = offs[blockIdx.x];
#pragma unroll
    for (int t = 0; t < 4; ++t) {
        int i = base + t;
        if (i < NN) {
            int rp = row_ptr[i] + o;
            row_ptr[i] = rp;
            cursor[i] = rp;
        }
    }
    const int xbase = blockIdx.x * 32768;
    for (int t = 0; t < 128; ++t) {
        int idx = xbase + t * 256 + tid;
        if (idx < NN * 32) {
            int node = idx >> 5, f = idx & 31;
            xp[idx] = (f < IND) ? x[node * IND + f] * dinv[node] : 0.f;
        }
    }
}

__global__ void k_fill(const int* __restrict__ src, const int* __restrict__ dst,
                       int* __restrict__ cursor, int* __restrict__ e_src, int e) {
    int i = blockIdx.x * blockDim.x + threadIdx.x;
    if (i < e) {
        int d = dst[i];
        int pos = atomicAdd(&cursor[d], 1);
        e_src[pos] = src[i];
    }
}

// ---- layer 1 fused: q1 = quant( tanh( (A @ x) @ W1 + b1 ) ) ---------------
// wave per node; 8 edges in flight. Remainder shfl runs wave-uniform
// (ds_bpermute from an EXEC-masked source lane is undefined — round-6/7 bug).
__global__ __launch_bounds__(256) void k_l1(const float* __restrict__ xp,
                                            const float* __restrict__ W1,
                                            const float* __restrict__ b1,
                                            const int* __restrict__ row_ptr,
                                            const int* __restrict__ e_src,
                                            const float* __restrict__ dinv,
                                            short* __restrict__ outq) {
    const int tid = threadIdx.x;
    const int i = blockIdx.x * 4 + (tid >> 6);
    const int lane = tid & 63;
    const int slot = lane >> 3;     // 8 edge slots
    const int f = lane & 7;         // float4 index within 32-float row
    const float4* xp4 = (const float4*)xp;
    const int beg = row_ptr[i];
    const int deg = row_ptr[i + 1] - beg;
    float4 acc = make_float4(0.f, 0.f, 0.f, 0.f);
    for (int base = 0; base < deg; base += 64) {
        const int cnt = min(64, deg - base);
        int s_l = 0;
        if (lane < cnt) s_l = e_src[beg + base + lane];
        int e = 0;
        for (; e + 8 <= cnt; e += 8) {
            int s = __shfl(s_l, e + slot, 64);
            float4 v = xp4[s * 8 + f];
            acc.x += v.x; acc.y += v.y; acc.z += v.z; acc.w += v.w;
        }
        if (e < cnt) {                          // wave-uniform shfl
            int s = __shfl(s_l, e + slot, 64);
            if (e + slot < cnt) {
                float4 v = xp4[s * 8 + f];
                acc.x += v.x; acc.y += v.y; acc.z += v.z; acc.w += v.w;
            }
        }
    }
#pragma unroll
    for (int off = 32; off >= 8; off >>= 1) {
        acc.x += __shfl_down(acc.x, off, 64);
        acc.y += __shfl_down(acc.y, off, 64);
        acc.z += __shfl_down(acc.z, off, 64);
        acc.w += __shfl_down(acc.w, off, 64);
    }
    const float di = dinv[i];
    if (lane < 8) {
        float4 v = xp4[i * 8 + lane];   // self row (pre-folded)
        acc.x = (acc.x + v.x) * di; acc.y = (acc.y + v.y) * di;
        acc.z = (acc.z + v.z) * di; acc.w = (acc.w + v.w) * di;
    }
    float a0 = b1[lane], a1 = b1[lane + 64];
#pragma unroll
    for (int k = 0; k < IND; ++k) {
        float comp = ((k & 3) == 0) ? acc.x : ((k & 3) == 1) ? acc.y
                   : ((k & 3) == 2) ? acc.z : acc.w;
        float xk = __shfl(comp, k >> 2, 64);
        a0 += xk * W1[k * HID + lane];
        a1 += xk * W1[k * HID + lane + 64];
    }
    outq[i * HID + lane]      = (short)__float2int_rn(tanhf(a0) * QS);
    outq[i * HID + lane + 64] = (short)__float2int_rn(tanhf(a1) * QS);
}

// ---- aggregation over int16 tanh rows (lean: low VGPR, 0 LDS, high occ) ---
// aggf_i = dinv_i * ( sum_s dinv_s*q_s + dinv_i*q_i ) / QS
__global__ __launch_bounds__(256) void k_aggq(const short* __restrict__ hq,
                                              const int* __restrict__ row_ptr,
                                              const int* __restrict__ e_src,
                                              const float* __restrict__ dinv,
                                              float* __restrict__ aggf) {
    const int tid = threadIdx.x;
    const int i = blockIdx.x * 4 + (tid >> 6);
    const int lane = tid & 63;
    const int slot = lane >> 4;     // 4 edge slots
    const int f = lane & 15;        // short8 index within 128-short row
    const short8v* h8 = (const short8v*)hq;
    const int beg = row_ptr[i];
    const int deg = row_ptr[i + 1] - beg;
    float facc[8];
#pragma unroll
    for (int t = 0; t < 8; ++t) facc[t] = 0.f;
    for (int base = 0; base < deg; base += 64) {
        const int cnt = min(64, deg - base);
        int s_l = 0; float n_l = 0.f;
        if (lane < cnt) {
            s_l = e_src[beg + base + lane];
            n_l = dinv[s_l];
        }
        int e = 0;
#pragma unroll 2
        for (; e + 4 <= cnt; e += 4) {
            int s = __shfl(s_l, e + slot, 64);
            float nr = __shfl(n_l, e + slot, 64);
            short8v v = h8[s * 16 + f];
#pragma unroll
            for (int t = 0; t < 8; ++t) facc[t] += (float)v[t] * nr;
        }
        if (e < cnt) {                          // wave-uniform shfl
            int s = __shfl(s_l, e + slot, 64);
            float nr = __shfl(n_l, e + slot, 64);
            if (e + slot < cnt) {
                short8v v = h8[s * 16 + f];
#pragma unroll
                for (int t = 0; t < 8; ++t) facc[t] += (float)v[t] * nr;
            }
        }
    }
#pragma unroll
    for (int off = 32; off >= 16; off >>= 1)
#pragma unroll
        for (int t = 0; t < 8; ++t) facc[t] += __shfl_down(facc[t], off, 64);
    if (lane < 16) {
        const float di = dinv[i];
        const float sc = di * INVQS;
        short8v v = h8[i * 16 + lane];          // self row
        float4 o0, o1;
        o0.x = (facc[0] + di * (float)v[0]) * sc;
        o0.y = (facc[1] + di * (float)v[1]) * sc;
        o0.z = (facc[2] + di * (float)v[2]) * sc;
        o0.w = (facc[3] + di * (float)v[3]) * sc;
        o1.x = (facc[4] + di * (float)v[4]) * sc;
        o1.y = (facc[5] + di * (float)v[5]) * sc;
        o1.z = (facc[6] + di * (float)v[6]) * sc;
        o1.w = (facc[7] + di * (float)v[7]) * sc;
        ((float4*)aggf)[i * 32 + lane * 2]     = o0;
        ((float4*)aggf)[i * 32 + lane * 2 + 1] = o1;
    }
}

// ---- tiled 128x128 GEMM with tanh epilogue (25.6 KB LDS — keep it lean) ---
// out = tanh(hin @ W + b); qout: int16 quantized; fout: fp32 (in-place safe:
// each block reads only its own 64 rows of hin before writing them).
__global__ __launch_bounds__(256) void k_gemmT(const float* __restrict__ hin,
                                               const float* __restrict__ W,
                                               const float* __restrict__ bias,
                                               short* __restrict__ qout,
                                               float* __restrict__ fout) {
    __shared__ float Hs[64 * 36];
    __shared__ float Ws[32 * 128];
    const int tid = threadIdx.x;
    const int b0 = blockIdx.x * 64;
    const int ng = tid >> 4;
    const int cg = tid & 15;
    const float4* hin4 = (const float4*)hin;
    const float4* W4 = (const float4*)W;

    float acc[4][8];
#pragma unroll
    for (int m = 0; m < 4; ++m)
#pragma unroll
        for (int c = 0; c < 8; ++c) acc[m][c] = 0.f;

    for (int ks = 0; ks < HID; ks += 32) {
#pragma unroll
        for (int t = 0; t < 2; ++t) {
            int id = t * 256 + tid;
            int row = id >> 3;
            int k4 = id & 7;
            int node = b0 + row;
            float4 v = make_float4(0.f, 0.f, 0.f, 0.f);
            if (node < NN) v = hin4[node * 32 + (ks >> 2) + k4];
            *(float4*)&Hs[row * 36 + k4 * 4] = v;
        }
#pragma unroll
        for (int t = 0; t < 4; ++t) {
            int id = t * 256 + tid;
            int row = id >> 5;
            int c4 = id & 31;
            *(float4*)&Ws[row * 128 + c4 * 4] = W4[(ks + row) * 32 + c4];
        }
        __syncthreads();
#pragma unroll 8
        for (int kk = 0; kk < 32; ++kk) {
            float4 w0 = *(float4*)&Ws[kk * 128 + cg * 8];
            float4 w1 = *(float4*)&Ws[kk * 128 + cg * 8 + 4];
#pragma unroll
            for (int m = 0; m < 4; ++m) {
                float hv = Hs[(ng * 4 + m) * 36 + kk];
                acc[m][0] += hv * w0.x; acc[m][1] += hv * w0.y;
                acc[m][2] += hv * w0.z; acc[m][3] += hv * w0.w;
                acc[m][4] += hv * w1.x; acc[m][5] += hv * w1.y;
                acc[m][6] += hv * w1.z; acc[m][7] += hv * w1.w;
            }
        }
        __syncthreads();
    }
    const float4* b4 = (const float4*)bias;
    float4 bb0 = b4[cg * 2], bb1 = b4[cg * 2 + 1];
#pragma unroll
    for (int m = 0; m < 4; ++m) {
        int node = b0 + ng * 4 + m;
        if (node < NN) {
            float t0 = tanhf(acc[m][0] + bb0.x);
            float t1 = tanhf(acc[m][1] + bb0.y);
            float t2 = tanhf(acc[m][2] + bb0.z);
            float t3 = tanhf(acc[m][3] + bb0.w);
            float t4 = tanhf(acc[m][4] + bb1.x);
            float t5 = tanhf(acc[m][5] + bb1.y);
            float t6 = tanhf(acc[m][6] + bb1.z);
            float t7 = tanhf(acc[m][7] + bb1.w);
            if (qout) {
                short8v qv;
                qv[0] = (short)__float2int_rn(t0 * QS);
                qv[1] = (short)__float2int_rn(t1 * QS);
                qv[2] = (short)__float2int_rn(t2 * QS);
                qv[3] = (short)__float2int_rn(t3 * QS);
                qv[4] = (short)__float2int_rn(t4 * QS);
                qv[5] = (short)__float2int_rn(t5 * QS);
                qv[6] = (short)__float2int_rn(t6 * QS);
                qv[7] = (short)__float2int_rn(t7 * QS);
                ((short8v*)qout)[node * 16 + cg] = qv;
            }
            if (fout) {
                ((float4*)fout)[node * 32 + cg * 2]     = make_float4(t0, t1, t2, t3);
                ((float4*)fout)[node * 32 + cg * 2 + 1] = make_float4(t4, t5, t6, t7);
            }
        }
    }
}

// ---- classifier head: 16 nodes/block, 128 -> 64 -> 12 (separate & lean) ---

__global__ __launch_bounds__(256) void k_cls(const float* __restrict__ h,
                                             const float* __restrict__ Wc1,
                                             const float* __restrict__ bc1,
                                             const float* __restrict__ Wc2,
                                             const float* __restrict__ bc2,
                                             float* __restrict__ out) {
    __shared__ float hs[16 * 128];
    __shared__ float ms[16 * 65];
    const int tid = threadIdx.x;
    const int b0 = blockIdx.x * 16;
    const float4* h4 = (const float4*)h;
#pragma unroll
    for (int t = 0; t < 2; ++t) {
        int id = t * 256 + tid;
        int node = id >> 5;
        int k4 = id & 31;
        float4 v = make_float4(0.f, 0.f, 0.f, 0.f);
        if (b0 + node < NN) v = h4[(b0 + node) * 32 + k4];
        *(float4*)&hs[node * 128 + k4 * 4] = v;
    }
    __syncthreads();
    const int q = tid >> 6;
    const int c = tid & 63;
    float acc[4];
#pragma unroll
    for (int t = 0; t < 4; ++t) acc[t] = 0.f;
    for (int k = 0; k < HID; ++k) {
        float w = Wc1[k * MIDD + c];
#pragma unroll
        for (int t = 0; t < 4; ++t) acc[t] += hs[(q + 4 * t) * 128 + k] * w;
    }
    float bb = bc1[c];
#pragma unroll
    for (int t = 0; t < 4; ++t) ms[(q + 4 * t) * 65 + c] = acc[t] + bb;
    __syncthreads();
    if (tid < 16 * NCLS) {
        int m = tid / NCLS;
        int cls = tid % NCLS;
        int node = b0 + m;
        if (node < NN) {
            float o = bc2[cls];
#pragma unroll 8
            for (int k = 0; k < MIDD; ++k) o += ms[m * 65 + k] * Wc2[k * NCLS + cls];
            out[node * NCLS + cls] = o;
        }
    }
}

// ---- launch ---------------------------------------------------------------

extern "C" void kernel_launch(void* const* d_in, const int* in_sizes, int n_in,
                              void* d_out, int out_size, void* d_ws, size_t ws_size,
                              hipStream_t stream) {
    const float* x    = (const float*)d_in[0];
    const int*   edge = (const int*)d_in[1];
    const int*   src  = edge;
    const int*   dst  = edge + EE;
    const float* W1  = (const float*)d_in[2];  const float* b1  = (const float*)d_in[3];
    const float* W2  = (const float*)d_in[4];  const float* b2  = (const float*)d_in[5];
    const float* W3  = (const float*)d_in[6];  const float* b3  = (const float*)d_in[7];
    const float* Wc1 = (const float*)d_in[8];  const float* bc1 = (const float*)d_in[9];
    const float* Wc2 = (const float*)d_in[10]; const float* bc2 = (const float*)d_in[11];
    float* outp = (float*)d_out;

    char* p = (char*)d_ws;
    int*   cnt     = (int*)p;   p += 200064;          // NN ints, padded
    int*   row_ptr = (int*)p;   p += 200064;          // NN+1 ints, padded
    float* dinv    = (float*)p; p += 200064;
    int*   sums    = (int*)p;   p += 256;
    int*   offs    = (int*)p;   p += 256;
    int*   e_src   = (int*)p;   p += (size_t)EE * 4;
    float* xp      = (float*)p; p += (size_t)NN * 32 * 4;    // padded pre-folded x
    short* q       = (short*)p; p += (size_t)NN * HID * 2;   // int16 tanh (q1/q2 alias)
    float* aggf    = (float*)p; p += (size_t)NN * HID * 4;   // fp32 agg / h3 (in-place)

    // graph build (+x pad folded into scan_apply)
    hipMemsetAsync(cnt, 0, (size_t)NN * 4, stream);
    k_count     <<<(EE + 255) / 256, 256, 0, stream>>>(dst, cnt, EE);
    k_scan_local<<<NB, 256, 0, stream>>>(cnt, row_ptr, dinv, sums);
    k_scan_sums <<<1, 64, 0, stream>>>(sums, offs, row_ptr);
    k_scan_apply<<<NB, 256, 0, stream>>>(row_ptr, offs, cnt, x, dinv, xp);
    k_fill      <<<(EE + 255) / 256, 256, 0, stream>>>(src, dst, cnt, e_src, EE);

    // layer 1: q1 = quant(tanh((A@x)@W1 + b1))
    k_l1  <<<NN / 4, 256, 0, stream>>>(xp, W1, b1, row_ptr, e_src, dinv, q);
    // layer 2: agg(q1) -> gemm+tanh -> q2   (q2 aliases q1; stream-ordered)
    k_aggq <<<NN / 4, 256, 0, stream>>>(q, row_ptr, e_src, dinv, aggf);
    k_gemmT<<<(NN + 63) / 64, 256, 0, stream>>>(aggf, W2, b2, q, nullptr);
    // layer 3: agg(q2) -> gemm+tanh -> h3 fp32 (in-place over aggf)
    k_aggq <<<NN / 4, 256, 0, stream>>>(q, row_ptr, e_src, dinv, aggf);
    k_gemmT<<<(NN + 63) / 64, 256, 0, stream>>>(aggf, W3, b3, nullptr, aggf);
    // head
    k_cls<<<(NN + 15) / 16, 256, 0, stream>>>(aggf, Wc1, bc1, Wc2, bc2, outp);
}

// Round 12
// 339.905 us; speedup vs baseline: 1.3094x; 1.0923x over previous
//
#include <hip/hip_runtime.h>
#include <math.h>

#define NN 50000
#define EE 640000
#define IND 23
#define HID 128
#define MIDD 64
#define NCLS 12
#define NB 49          // ceil(NN / 1024) scan chunks
#define QS 32766.0f
#define INVQS (1.0f / 32766.0f)

typedef short short8v __attribute__((ext_vector_type(8)));

// ---- graph build ----------------------------------------------------------

__global__ void k_count(const int* __restrict__ dst, int* __restrict__ cnt, int e) {
    int i = blockIdx.x * blockDim.x + threadIdx.x;
    if (i < e) atomicAdd(&cnt[dst[i]], 1);
}

__global__ __launch_bounds__(256) void k_scan_local(const int* __restrict__ cnt,
                                                    int* __restrict__ row_ptr,
                                                    float* __restrict__ dinv,
                                                    int* __restrict__ sums) {
    __shared__ int wtot[4];
    const int tid = threadIdx.x;
    const int wid = tid >> 6, lane = tid & 63;
    const int base = blockIdx.x * 1024 + tid * 4;
    int v[4];
#pragma unroll
    for (int t = 0; t < 4; ++t) {
        int i = base + t;
        v[t] = (i < NN) ? cnt[i] : 0;
        if (i < NN) dinv[i] = rsqrtf((float)v[t] + 1.0f);  // +1 self loop
    }
    int slocal = v[0] + v[1] + v[2] + v[3];
    int val = slocal;
#pragma unroll
    for (int off = 1; off < 64; off <<= 1) {
        int t = __shfl_up(val, off, 64);
        if (lane >= off) val += t;
    }
    if (lane == 63) wtot[wid] = val;
    __syncthreads();
    int woff = 0;
#pragma unroll
    for (int w = 0; w < 4; ++w) woff += (w < wid) ? wtot[w] : 0;
    int run = woff + val - slocal;
#pragma unroll
    for (int t = 0; t < 4; ++t) {
        int i = base + t;
        if (i < NN) row_ptr[i] = run;
        run += v[t];
    }
    if (tid == 255) sums[blockIdx.x] = woff + val;
}

__global__ void k_scan_sums(const int* __restrict__ sums, int* __restrict__ offs,
                            int* __restrict__ row_ptr) {
    const int lane = threadIdx.x;
    int v = (lane < NB) ? sums[lane] : 0;
    int val = v;
#pragma unroll
    for (int off = 1; off < 64; off <<= 1) {
        int t = __shfl_up(val, off, 64);
        if (lane >= off) val += t;
    }
    if (lane < NB) offs[lane] = val - v;
    if (lane == NB - 1) row_ptr[NN] = val;
}

// lean 49-block scan finalize ONLY (pad lives in its own wide launch —
// merging it here collapsed to 2% occupancy and cost ~50 µs, round 11)
__global__ __launch_bounds__(256) void k_scan_apply(int* __restrict__ row_ptr,
                                                    const int* __restrict__ offs,
                                                    int* __restrict__ cursor) {
    const int base = blockIdx.x * 1024 + threadIdx.x * 4;
    const int o = offs[blockIdx.x];
#pragma unroll
    for (int t = 0; t < 4; ++t) {
        int i = base + t;
        if (i < NN) {
            int rp = row_ptr[i] + o;
            row_ptr[i] = rp;
            cursor[i] = rp;
        }
    }
}

__global__ void k_fill(const int* __restrict__ src, const int* __restrict__ dst,
                       int* __restrict__ cursor, int* __restrict__ e_src, int e) {
    int i = blockIdx.x * blockDim.x + threadIdx.x;
    if (i < e) {
        int d = dst[i];
        int pos = atomicAdd(&cursor[d], 1);
        e_src[pos] = src[i];
    }
}

// pad x rows 23 -> 32 floats, pre-scaled by dinv[node] (wide 6250-block grid)
__global__ __launch_bounds__(256) void k_pad(const float* __restrict__ x,
                                             const float* __restrict__ dinv,
                                             float* __restrict__ xp) {
    int i = blockIdx.x * 256 + threadIdx.x;   // over NN*32
    int node = i >> 5, f = i & 31;
    xp[i] = (f < IND) ? x[node * IND + f] * dinv[node] : 0.f;
}

// ---- layer 1 fused: q1 = quant( tanh( (A @ x) @ W1 + b1 ) ) ---------------
// wave per node; 8 edges in flight. Remainder shfl runs wave-uniform
// (ds_bpermute from an EXEC-masked source lane is undefined — round-6/7 bug).
__global__ __launch_bounds__(256) void k_l1(const float* __restrict__ xp,
                                            const float* __restrict__ W1,
                                            const float* __restrict__ b1,
                                            const int* __restrict__ row_ptr,
                                            const int* __restrict__ e_src,
                                            const float* __restrict__ dinv,
                                            short* __restrict__ outq) {
    const int tid = threadIdx.x;
    const int i = blockIdx.x * 4 + (tid >> 6);
    const int lane = tid & 63;
    const int slot = lane >> 3;     // 8 edge slots
    const int f = lane & 7;         // float4 index within 32-float row
    const float4* xp4 = (const float4*)xp;
    const int beg = row_ptr[i];
    const int deg = row_ptr[i + 1] - beg;
    float4 acc = make_float4(0.f, 0.f, 0.f, 0.f);
    for (int base = 0; base < deg; base += 64) {
        const int cnt = min(64, deg - base);
        int s_l = 0;
        if (lane < cnt) s_l = e_src[beg + base + lane];
        int e = 0;
        for (; e + 8 <= cnt; e += 8) {
            int s = __shfl(s_l, e + slot, 64);
            float4 v = xp4[s * 8 + f];
            acc.x += v.x; acc.y += v.y; acc.z += v.z; acc.w += v.w;
        }
        if (e < cnt) {                          // wave-uniform shfl
            int s = __shfl(s_l, e + slot, 64);
            if (e + slot < cnt) {
                float4 v = xp4[s * 8 + f];
                acc.x += v.x; acc.y += v.y; acc.z += v.z; acc.w += v.w;
            }
        }
    }
#pragma unroll
    for (int off = 32; off >= 8; off >>= 1) {
        acc.x += __shfl_down(acc.x, off, 64);
        acc.y += __shfl_down(acc.y, off, 64);
        acc.z += __shfl_down(acc.z, off, 64);
        acc.w += __shfl_down(acc.w, off, 64);
    }
    const float di = dinv[i];
    if (lane < 8) {
        float4 v = xp4[i * 8 + lane];   // self row (pre-folded)
        acc.x = (acc.x + v.x) * di; acc.y = (acc.y + v.y) * di;
        acc.z = (acc.z + v.z) * di; acc.w = (acc.w + v.w) * di;
    }
    float a0 = b1[lane], a1 = b1[lane + 64];
#pragma unroll
    for (int k = 0; k < IND; ++k) {
        float comp = ((k & 3) == 0) ? acc.x : ((k & 3) == 1) ? acc.y
                   : ((k & 3) == 2) ? acc.z : acc.w;
        float xk = __shfl(comp, k >> 2, 64);
        a0 += xk * W1[k * HID + lane];
        a1 += xk * W1[k * HID + lane + 64];
    }
    outq[i * HID + lane]      = (short)__float2int_rn(tanhf(a0) * QS);
    outq[i * HID + lane + 64] = (short)__float2int_rn(tanhf(a1) * QS);
}

// ---- aggregation over int16 tanh rows (lean: low VGPR, 0 LDS, high occ) ---
// aggf_i = dinv_i * ( sum_s dinv_s*q_s + dinv_i*q_i ) / QS
__global__ __launch_bounds__(256) void k_aggq(const short* __restrict__ hq,
                                              const int* __restrict__ row_ptr,
                                              const int* __restrict__ e_src,
                                              const float* __restrict__ dinv,
                                              float* __restrict__ aggf) {
    const int tid = threadIdx.x;
    const int i = blockIdx.x * 4 + (tid >> 6);
    const int lane = tid & 63;
    const int slot = lane >> 4;     // 4 edge slots
    const int f = lane & 15;        // short8 index within 128-short row
    const short8v* h8 = (const short8v*)hq;
    const int beg = row_ptr[i];
    const int deg = row_ptr[i + 1] - beg;
    float facc[8];
#pragma unroll
    for (int t = 0; t < 8; ++t) facc[t] = 0.f;
    for (int base = 0; base < deg; base += 64) {
        const int cnt = min(64, deg - base);
        int s_l = 0; float n_l = 0.f;
        if (lane < cnt) {
            s_l = e_src[beg + base + lane];
            n_l = dinv[s_l];
        }
        int e = 0;
#pragma unroll 2
        for (; e + 4 <= cnt; e += 4) {
            int s = __shfl(s_l, e + slot, 64);
            float nr = __shfl(n_l, e + slot, 64);
            short8v v = h8[s * 16 + f];
#pragma unroll
            for (int t = 0; t < 8; ++t) facc[t] += (float)v[t] * nr;
        }
        if (e < cnt) {                          // wave-uniform shfl
            int s = __shfl(s_l, e + slot, 64);
            float nr = __shfl(n_l, e + slot, 64);
            if (e + slot < cnt) {
                short8v v = h8[s * 16 + f];
#pragma unroll
                for (int t = 0; t < 8; ++t) facc[t] += (float)v[t] * nr;
            }
        }
    }
#pragma unroll
    for (int off = 32; off >= 16; off >>= 1)
#pragma unroll
        for (int t = 0; t < 8; ++t) facc[t] += __shfl_down(facc[t], off, 64);
    if (lane < 16) {
        const float di = dinv[i];
        const float sc = di * INVQS;
        short8v v = h8[i * 16 + lane];          // self row
        float4 o0, o1;
        o0.x = (facc[0] + di * (float)v[0]) * sc;
        o0.y = (facc[1] + di * (float)v[1]) * sc;
        o0.z = (facc[2] + di * (float)v[2]) * sc;
        o0.w = (facc[3] + di * (float)v[3]) * sc;
        o1.x = (facc[4] + di * (float)v[4]) * sc;
        o1.y = (facc[5] + di * (float)v[5]) * sc;
        o1.z = (facc[6] + di * (float)v[6]) * sc;
        o1.w = (facc[7] + di * (float)v[7]) * sc;
        ((float4*)aggf)[i * 32 + lane * 2]     = o0;
        ((float4*)aggf)[i * 32 + lane * 2 + 1] = o1;
    }
}

// ---- tiled 128x128 GEMM with tanh epilogue (25.6 KB LDS — keep it lean) ---
// out = tanh(hin @ W + b); qout: int16 quantized; fout: fp32 (in-place safe:
// each block reads only its own 64 rows of hin before writing them).
__global__ __launch_bounds__(256) void k_gemmT(const float* __restrict__ hin,
                                               const float* __restrict__ W,
                                               const float* __restrict__ bias,
                                               short* __restrict__ qout,
                                               float* __restrict__ fout) {
    __shared__ float Hs[64 * 36];
    __shared__ float Ws[32 * 128];
    const int tid = threadIdx.x;
    const int b0 = blockIdx.x * 64;
    const int ng = tid >> 4;
    const int cg = tid & 15;
    const float4* hin4 = (const float4*)hin;
    const float4* W4 = (const float4*)W;

    float acc[4][8];
#pragma unroll
    for (int m = 0; m < 4; ++m)
#pragma unroll
        for (int c = 0; c < 8; ++c) acc[m][c] = 0.f;

    for (int ks = 0; ks < HID; ks += 32) {
#pragma unroll
        for (int t = 0; t < 2; ++t) {
            int id = t * 256 + tid;
            int row = id >> 3;
            int k4 = id & 7;
            int node = b0 + row;
            float4 v = make_float4(0.f, 0.f, 0.f, 0.f);
            if (node < NN) v = hin4[node * 32 + (ks >> 2) + k4];
            *(float4*)&Hs[row * 36 + k4 * 4] = v;
        }
#pragma unroll
        for (int t = 0; t < 4; ++t) {
            int id = t * 256 + tid;
            int row = id >> 5;
            int c4 = id & 31;
            *(float4*)&Ws[row * 128 + c4 * 4] = W4[(ks + row) * 32 + c4];
        }
        __syncthreads();
#pragma unroll 8
        for (int kk = 0; kk < 32; ++kk) {
            float4 w0 = *(float4*)&Ws[kk * 128 + cg * 8];
            float4 w1 = *(float4*)&Ws[kk * 128 + cg * 8 + 4];
#pragma unroll
            for (int m = 0; m < 4; ++m) {
                float hv = Hs[(ng * 4 + m) * 36 + kk];
                acc[m][0] += hv * w0.x; acc[m][1] += hv * w0.y;
                acc[m][2] += hv * w0.z; acc[m][3] += hv * w0.w;
                acc[m][4] += hv * w1.x; acc[m][5] += hv * w1.y;
                acc[m][6] += hv * w1.z; acc[m][7] += hv * w1.w;
            }
        }
        __syncthreads();
    }
    const float4* b4 = (const float4*)bias;
    float4 bb0 = b4[cg * 2], bb1 = b4[cg * 2 + 1];
#pragma unroll
    for (int m = 0; m < 4; ++m) {
        int node = b0 + ng * 4 + m;
        if (node < NN) {
            float t0 = tanhf(acc[m][0] + bb0.x);
            float t1 = tanhf(acc[m][1] + bb0.y);
            float t2 = tanhf(acc[m][2] + bb0.z);
            float t3 = tanhf(acc[m][3] + bb0.w);
            float t4 = tanhf(acc[m][4] + bb1.x);
            float t5 = tanhf(acc[m][5] + bb1.y);
            float t6 = tanhf(acc[m][6] + bb1.z);
            float t7 = tanhf(acc[m][7] + bb1.w);
            if (qout) {
                short8v qv;
                qv[0] = (short)__float2int_rn(t0 * QS);
                qv[1] = (short)__float2int_rn(t1 * QS);
                qv[2] = (short)__float2int_rn(t2 * QS);
                qv[3] = (short)__float2int_rn(t3 * QS);
                qv[4] = (short)__float2int_rn(t4 * QS);
                qv[5] = (short)__float2int_rn(t5 * QS);
                qv[6] = (short)__float2int_rn(t6 * QS);
                qv[7] = (short)__float2int_rn(t7 * QS);
                ((short8v*)qout)[node * 16 + cg] = qv;
            }
            if (fout) {
                ((float4*)fout)[node * 32 + cg * 2]     = make_float4(t0, t1, t2, t3);
                ((float4*)fout)[node * 32 + cg * 2 + 1] = make_float4(t4, t5, t6, t7);
            }
        }
    }
}

// ---- classifier head: 16 nodes/block, 128 -> 64 -> 12 (separate & lean) ---

__global__ __launch_bounds__(256) void k_cls(const float* __restrict__ h,
                                             const float* __restrict__ Wc1,
                                             const float* __restrict__ bc1,
                                             const float* __restrict__ Wc2,
                                             const float* __restrict__ bc2,
                                             float* __restrict__ out) {
    __shared__ float hs[16 * 128];
    __shared__ float ms[16 * 65];
    const int tid = threadIdx.x;
    const int b0 = blockIdx.x * 16;
    const float4* h4 = (const float4*)h;
#pragma unroll
    for (int t = 0; t < 2; ++t) {
        int id = t * 256 + tid;
        int node = id >> 5;
        int k4 = id & 31;
        float4 v = make_float4(0.f, 0.f, 0.f, 0.f);
        if (b0 + node < NN) v = h4[(b0 + node) * 32 + k4];
        *(float4*)&hs[node * 128 + k4 * 4] = v;
    }
    __syncthreads();
    const int q = tid >> 6;
    const int c = tid & 63;
    float acc[4];
#pragma unroll
    for (int t = 0; t < 4; ++t) acc[t] = 0.f;
    for (int k = 0; k < HID; ++k) {
        float w = Wc1[k * MIDD + c];
#pragma unroll
        for (int t = 0; t < 4; ++t) acc[t] += hs[(q + 4 * t) * 128 + k] * w;
    }
    float bb = bc1[c];
#pragma unroll
    for (int t = 0; t < 4; ++t) ms[(q + 4 * t) * 65 + c] = acc[t] + bb;
    __syncthreads();
    if (tid < 16 * NCLS) {
        int m = tid / NCLS;
        int cls = tid % NCLS;
        int node = b0 + m;
        if (node < NN) {
            float o = bc2[cls];
#pragma unroll 8
            for (int k = 0; k < MIDD; ++k) o += ms[m * 65 + k] * Wc2[k * NCLS + cls];
            out[node * NCLS + cls] = o;
        }
    }
}

// ---- launch ---------------------------------------------------------------

extern "C" void kernel_launch(void* const* d_in, const int* in_sizes, int n_in,
                              void* d_out, int out_size, void* d_ws, size_t ws_size,
                              hipStream_t stream) {
    const float* x    = (const float*)d_in[0];
    const int*   edge = (const int*)d_in[1];
    const int*   src  = edge;
    const int*   dst  = edge + EE;
    const float* W1  = (const float*)d_in[2];  const float* b1  = (const float*)d_in[3];
    const float* W2  = (const float*)d_in[4];  const float* b2  = (const float*)d_in[5];
    const float* W3  = (const float*)d_in[6];  const float* b3  = (const float*)d_in[7];
    const float* Wc1 = (const float*)d_in[8];  const float* bc1 = (const float*)d_in[9];
    const float* Wc2 = (const float*)d_in[10]; const float* bc2 = (const float*)d_in[11];
    float* outp = (float*)d_out;

    char* p = (char*)d_ws;
    int*   cnt     = (int*)p;   p += 200064;          // NN ints, padded
    int*   row_ptr = (int*)p;   p += 200064;          // NN+1 ints, padded
    float* dinv    = (float*)p; p += 200064;
    int*   sums    = (int*)p;   p += 256;
    int*   offs    = (int*)p;   p += 256;
    int*   e_src   = (int*)p;   p += (size_t)EE * 4;
    float* xp      = (float*)p; p += (size_t)NN * 32 * 4;    // padded pre-folded x
    short* q       = (short*)p; p += (size_t)NN * HID * 2;   // int16 tanh (q1/q2 alias)
    float* aggf    = (float*)p; p += (size_t)NN * HID * 4;   // fp32 agg / h3 (in-place)

    // graph build
    hipMemsetAsync(cnt, 0, (size_t)NN * 4, stream);
    k_count     <<<(EE + 255) / 256, 256, 0, stream>>>(dst, cnt, EE);
    k_scan_local<<<NB, 256, 0, stream>>>(cnt, row_ptr, dinv, sums);
    k_scan_sums <<<1, 64, 0, stream>>>(sums, offs, row_ptr);
    k_scan_apply<<<NB, 256, 0, stream>>>(row_ptr, offs, cnt);   // cnt becomes cursor
    k_fill      <<<(EE + 255) / 256, 256, 0, stream>>>(src, dst, cnt, e_src, EE);
    k_pad       <<<(NN * 32) / 256, 256, 0, stream>>>(x, dinv, xp);

    // layer 1: q1 = quant(tanh((A@x)@W1 + b1))
    k_l1  <<<NN / 4, 256, 0, stream>>>(xp, W1, b1, row_ptr, e_src, dinv, q);
    // layer 2: agg(q1) -> gemm+tanh -> q2   (q2 aliases q1; stream-ordered)
    k_aggq <<<NN / 4, 256, 0, stream>>>(q, row_ptr, e_src, dinv, aggf);
    k_gemmT<<<(NN + 63) / 64, 256, 0, stream>>>(aggf, W2, b2, q, nullptr);
    // layer 3: agg(q2) -> gemm+tanh -> h3 fp32 (in-place over aggf)
    k_aggq <<<NN / 4, 256, 0, stream>>>(q, row_ptr, e_src, dinv, aggf);
    k_gemmT<<<(NN + 63) / 64, 256, 0, stream>>>(aggf, W3, b3, nullptr, aggf);
    // head
    k_cls<<<(NN + 15) / 16, 256, 0, stream>>>(aggf, Wc1, bc1, Wc2, bc2, outp);
}